// Round 12
// baseline (635.800 us; speedup 1.0000x reference)
//
#include <hip/hip_runtime.h>
#include <hip/hip_bf16.h>
#include <stdint.h>

typedef __attribute__((ext_vector_type(4))) float f32x4;
typedef __attribute__((ext_vector_type(4))) int i32x4;
typedef __attribute__((ext_vector_type(8))) int i32x8;

#define D_DIM 2048
#define V_DIM 32768
#define M_DIM 4096
#define N_SEQ 2048
#define K_TOP 64
#define NSLOT 512   // 128 v-tiles * 4 wc
#define EBCAP 512   // entries per 256x256 tile (avg ~130)
#define WSCALE 64.0f
#define IWSCALE 0.015625f

// ---------- helpers ----------
static __device__ __forceinline__ unsigned int f32_to_e4m3(float x) {
  float ax = fminf(fabsf(x), 448.0f);
  unsigned int s = (__float_as_uint(x) >> 31) << 7;
  if (ax >= 0.015625f) {
    unsigned int m = __float_as_uint(ax);
    unsigned int keep = m >> 20;
    unsigned int rb = (m >> 19) & 1u, st = (m & 0x7FFFFu) != 0u;
    keep += rb & (st | (keep & 1u));
    int v = (int)keep - (120 << 3);
    if (v > 0x7E) v = 0x7E;
    return s | (unsigned int)v;
  } else {
    int m = __float2int_rn(ax * 512.0f);
    return s | (unsigned int)m;
  }
}

typedef __attribute__((address_space(3))) unsigned int lds_u32_t;
typedef const __attribute__((address_space(1))) unsigned int glb_u32_t;
static __device__ __forceinline__ void gload16(const void* g, void* l) {
  __builtin_amdgcn_global_load_lds((glb_u32_t*)g, (lds_u32_t*)l, 16, 0, 0);
}

// ---------- cast f32 -> fp8 e4m3, LINEAR layout (W scaled x64) ----------
__global__ void cast_fp8_kernel(const float4* __restrict__ inA, uint2* __restrict__ outA, int nA8,
                                const float4* __restrict__ inB, uint2* __restrict__ outB, int nB8) {
  int i = blockIdx.x * blockDim.x + threadIdx.x;
  int stride = gridDim.x * blockDim.x;
  int tot = nA8 + nB8;
  for (; i < tot; i += stride) {
    const float4* in = (i < nA8) ? inA : inB;
    uint2* out = (i < nA8) ? outA : outB;
    float sc = (i < nA8) ? WSCALE : 1.0f;
    int j = (i < nA8) ? i : i - nA8;
    float4 a = in[2 * j], b = in[2 * j + 1];
    uint2 r;
    r.x = f32_to_e4m3(a.x * sc) | (f32_to_e4m3(a.y * sc) << 8) |
          (f32_to_e4m3(a.z * sc) << 16) | (f32_to_e4m3(a.w * sc) << 24);
    r.y = f32_to_e4m3(b.x * sc) | (f32_to_e4m3(b.y * sc) << 8) |
          (f32_to_e4m3(b.z * sc) << 16) | (f32_to_e4m3(b.w * sc) << 24);
    out[j] = r;
  }
}

// ---------- binning: (m, id) -> per-(mt,vt)-tile entry lists ----------
__global__ __launch_bounds__(256) void bin_kernel(
    const int* __restrict__ tids, const int* __restrict__ tlab,
    unsigned int* __restrict__ cnt, unsigned int* __restrict__ ebuf) {
  int idx = blockIdx.x * 256 + threadIdx.x;
  if (idx >= M_DIM * (K_TOP + 1)) return;
  int m = idx / (K_TOP + 1), k = idx - m * (K_TOP + 1);
  int id;
  if (k < K_TOP) id = tids[m * K_TOP + k];
  else {
    int n = m & (N_SEQ - 1);
    if (n == N_SEQ - 1) return;   // no gold for last position
    id = tlab[m + 1];
  }
  int tile = ((m >> 8) << 7) + (id >> 8);   // mt*128 + vt
  unsigned int pos = atomicAdd(&cnt[tile], 1u);
  if (pos < EBCAP)
    ebuf[tile * EBCAP + pos] =
        ((unsigned int)k << 16) | ((unsigned int)(m & 255) << 8) | (unsigned int)(id & 255);
}

// ---------- 256x256 GEMM, MX fp8 16x16x128 MFMA (unit scales) ----------
// 8 waves (2M x 4N), BK=128 (128 B/row fp8), 128KB LDS dbuf (16KB halves:
// pos0/1 = B rows 0-127/128-255, pos2/3 = A). Granule swizzle g ^= row&7
// (pre-applied on global src) -> 2-way max (r5-verified geometry).
// Lane fragment = 32 consecutive k-bytes = granules 2kqg,2kqg+1 (2x b128).
// Unit E8M0 scales (0x7F) -> math identical to plain fp8; acc descaled /64.
// 16 K-tiles, 4 segments/tile (1 barrier each), stage tile T+2 during T.

#define BAR do { __builtin_amdgcn_s_barrier(); asm volatile("" ::: "memory"); } while (0)
#define VMC(N) asm volatile("s_waitcnt vmcnt(" #N ")" ::: "memory")
#define PRIO1 __builtin_amdgcn_s_setprio(1)
#define PRIO0 __builtin_amdgcn_s_setprio(0)

#define LDQ(BASE, R, H) \
  (*(const i32x4*)((BASE) + (R) * 128 + (((2 * kqg + (H)) ^ ((R) & 7)) << 4)))
#define FRAG(DST, BASE, R) do { \
  i32x4 lo_ = LDQ(BASE, R, 0), hi_ = LDQ(BASE, R, 1); \
  DST = __builtin_shufflevector(lo_, hi_, 0, 1, 2, 3, 4, 5, 6, 7); \
} while (0)
#define FRAGA(DST, BASE, MI) FRAG(DST, BASE, (MI) * 16 + fr)
#define FRAGB(DST, BASE, NI) FRAG(DST, BASE, brow + (NI) * 16 + fr)

#define STAGE(H) do { \
  int tt_ = (H) >> 2, pos_ = (H) & 3; \
  char* dst_ = ldst + ((tt_ & 1) << 16) + (pos_ << 14); \
  const unsigned char* src_ = ((pos_ & 2) ? aptr : bptr) \
      + ((pos_ & 1) ? (size_t)128 * D_DIM : (size_t)0) + (size_t)tt_ * 128; \
  gload16(src_, dst_); \
  gload16(src_ + (size_t)64 * D_DIM, dst_ + 8192); \
} while (0)

#define MX(A_, B_, C_) __builtin_amdgcn_mfma_scale_f32_16x16x128_f8f6f4( \
    (A_), (B_), (C_), 0, 0, 0, 0x7F7F7F7F, 0, 0x7F7F7F7F)

#define MFMA_Q(M0, U0, U1) do { \
  _Pragma("unroll") \
  for (int ni = 0; ni < 4; ++ni) \
    acc[M0][ni] = MX(U0, bF[ni], acc[M0][ni]); \
  _Pragma("unroll") \
  for (int ni = 0; ni < 4; ++ni) \
    acc[(M0) + 1][ni] = MX(U1, bF[ni], acc[(M0) + 1][ni]); \
} while (0)

// Entering invariant: bF = B(T), a0/a1 = A mi0,1 of T (read in s4 of T-1 / prologue).
#define TILE1B(T, DOST, NVM, DONEXT) do { \
  char* curA_ = ldsAroot + (((T) & 1) << 16); \
  char* nxtA_ = ldsAroot + ((((T) + 1) & 1) << 16); \
  char* nxtB_ = ldsBroot + ((((T) + 1) & 1) << 16); \
  /* s1 */ \
  BAR; \
  if (DOST) STAGE(4 * (T) + 8); \
  PRIO1; MFMA_Q(0, a0, a1); PRIO0; \
  FRAGA(a2, curA_, 2); FRAGA(a3, curA_, 3); \
  /* s2 */ \
  BAR; \
  if (DOST) STAGE(4 * (T) + 9); \
  PRIO1; MFMA_Q(2, a2, a3); PRIO0; \
  FRAGA(a0, curA_, 4); FRAGA(a1, curA_, 5); \
  /* s3 */ \
  BAR; \
  PRIO1; MFMA_Q(4, a0, a1); PRIO0; \
  FRAGA(a2, curA_, 6); FRAGA(a3, curA_, 7); \
  if ((NVM) == 4) { VMC(4); } else if ((NVM) == 0) { VMC(0); } \
  /* s4 */ \
  BAR; \
  if (DOST) { STAGE(4 * (T) + 10); STAGE(4 * (T) + 11); } \
  PRIO1; MFMA_Q(6, a2, a3); PRIO0; \
  if (DONEXT) { \
    FRAGB(bF[0], nxtB_, 0); FRAGB(bF[1], nxtB_, 1); \
    FRAGB(bF[2], nxtB_, 2); FRAGB(bF[3], nxtB_, 3); \
    FRAGA(a0, nxtA_, 0); FRAGA(a1, nxtA_, 1); \
  } \
} while (0)

__global__ __launch_bounds__(512, 2) void gemm_lse_kernel(
    const unsigned char* __restrict__ x8,     // [M_DIM][D_DIM] fp8
    const unsigned char* __restrict__ w8,     // [V_DIM][D_DIM] fp8 (x64)
    float* __restrict__ pMax,                 // [M_DIM][NSLOT]
    float* __restrict__ pSum,
    const unsigned int* __restrict__ bcnt,    // [2048]
    const unsigned int* __restrict__ ebuf,    // [2048][EBCAP]
    float* __restrict__ gout) {               // [M_DIM][K_TOP+1]
  __shared__ __align__(16) char lds[131072];

  // Locality mapping (round-5): round of 256 blocks = 16mt x 16vt square;
  // each XCD pinned to 2 vt columns.
  const int bid0 = blockIdx.x;
  const int mt = (bid0 >> 4) & 15;
  const int vt = ((bid0 >> 8) << 4) | (bid0 & 15);
  const int tid = threadIdx.x, lane = tid & 63, w = tid >> 6;
  const int wr = w >> 2, wc = w & 3;
  const int fr = lane & 15, kqg = lane >> 4;
  const int brow = (wc & 1) * 64;

  // staging: thread t -> row t>>3 (+64 issue1, +128 pos&1), granule t&7;
  // src granule pre-swizzled (g ^ row&7)
  const int gcol = (((tid & 7) ^ ((tid >> 3) & 7)) << 4);
  const unsigned char* aptr = x8 + (size_t)(mt * 256 + (tid >> 3)) * D_DIM + gcol;
  const unsigned char* bptr = w8 + (size_t)(vt * 256 + (tid >> 3)) * D_DIM + gcol;
  char* ldst = lds + tid * 16;

  char* ldsAroot = lds + ((2 + wr) << 14);
  char* ldsBroot = lds + ((wc >> 1) << 14);

  f32x4 acc[8][4];
#pragma unroll
  for (int i = 0; i < 8; i++)
#pragma unroll
    for (int j = 0; j < 4; j++) acc[i][j] = (f32x4){0.f, 0.f, 0.f, 0.f};

  i32x8 bF[4], a0, a1, a2, a3;

  // prologue: stage tiles 0 and 1 fully (halves 0..7), drain, pre-read tile0
  STAGE(0); STAGE(1); STAGE(2); STAGE(3);
  STAGE(4); STAGE(5); STAGE(6); STAGE(7);
  VMC(0);
  BAR;
  FRAGB(bF[0], ldsBroot, 0); FRAGB(bF[1], ldsBroot, 1);
  FRAGB(bF[2], ldsBroot, 2); FRAGB(bF[3], ldsBroot, 3);
  FRAGA(a0, ldsAroot, 0); FRAGA(a1, ldsAroot, 1);

  // main loop: tiles 0..13 stage tile T+2; tail tiles 14, 15
  for (int it = 0; it < 7; ++it) {
    TILE1B(2 * it, 1, 4, 1);
    TILE1B(2 * it + 1, 1, 4, 1);
  }
  TILE1B(14, 0, 0, 1);
  TILE1B(15, 0, 99, 0);

  // ---- epilogue A: per-row (max, sumexp); descale acc by 1/64 ----
  const int slot = vt * 4 + wc;
#pragma unroll
  for (int mi = 0; mi < 8; mi++) {
#pragma unroll
    for (int j = 0; j < 4; j++) {
      const int row = mt * 256 + wr * 128 + mi * 16 + kqg * 4 + j;
      float v0 = acc[mi][0][j] * IWSCALE, v1 = acc[mi][1][j] * IWSCALE;
      float v2 = acc[mi][2][j] * IWSCALE, v3 = acc[mi][3][j] * IWSCALE;
      float mx = fmaxf(fmaxf(v0, v1), fmaxf(v2, v3));
      for (int s = 1; s < 16; s <<= 1) mx = fmaxf(mx, __shfl_xor(mx, s));
      float sm = __expf(v0 - mx) + __expf(v1 - mx) +
                 __expf(v2 - mx) + __expf(v3 - mx);
      for (int s = 1; s < 16; s <<= 1) sm += __shfl_xor(sm, s);
      if (fr == 0) {
        pMax[row * NSLOT + slot] = mx;
        pSum[row * NSLOT + slot] = sm;
      }
    }
  }

  // ---- epilogue B: fused gather of requested logits via LDS round-trip ----
  const int tile = (mt << 7) + vt;
  unsigned int cn = bcnt[tile];
  if (cn > EBCAP) cn = EBCAP;
  const unsigned int* elist = ebuf + tile * EBCAP;
  float* ldsf = (float*)lds;

  __syncthreads();
#pragma unroll
  for (int half = 0; half < 2; ++half) {
    if (wr == half) {
#pragma unroll
      for (int mi = 0; mi < 8; mi++) {
        const int r0 = mi * 16 + kqg * 4;
        const int cs = (kqg & 1) << 4;
#pragma unroll
        for (int ni = 0; ni < 4; ni++) {
          const int c0 = (wc * 64 + ni * 16 + fr) ^ cs;
#pragma unroll
          for (int j = 0; j < 4; j++)
            ldsf[(r0 + j) * 256 + c0] = acc[mi][ni][j] * IWSCALE;
        }
      }
    }
    __syncthreads();
    for (unsigned int e = tid; e < cn; e += 512) {
      unsigned int u = elist[e];
      int r = (u >> 8) & 255;
      if ((r >> 7) == half) {
        int c = u & 255, k = u >> 16;
        int rl = r & 127;
        gout[(mt * 256 + r) * (K_TOP + 1) + k] = ldsf[rl * 256 + (c ^ (((rl >> 2) & 1) << 4))];
      }
    }
    __syncthreads();
  }
}

// ---------- final: lse merge + CE + KD, atomic into scalar ----------
__global__ __launch_bounds__(256) void reduce_kernel(
    const float* __restrict__ pMax, const float* __restrict__ pSum,
    const float* __restrict__ gout, const float* __restrict__ t_lp,
    const int* __restrict__ t_mask, float* __restrict__ out) {
  const int tid = threadIdx.x, lane = tid & 63, w = tid >> 6;
  const int m = blockIdx.x * 4 + w;

  float msl[8], ssl[8];
  float M = -1e30f;
#pragma unroll
  for (int j = 0; j < 8; j++) {
    msl[j] = pMax[m * NSLOT + lane + j * 64];
    ssl[j] = pSum[m * NSLOT + lane + j * 64];
    M = fmaxf(M, msl[j]);
  }
  for (int s = 1; s < 64; s <<= 1) M = fmaxf(M, __shfl_xor(M, s));
  float S = 0.f;
#pragma unroll
  for (int j = 0; j < 8; j++) S += ssl[j] * __expf(msl[j] - M);
  for (int s = 1; s < 64; s <<= 1) S += __shfl_xor(S, s);
  const float lse = M + logf(S);

  const int n = m & (N_SEQ - 1);
  float ce = 0.f;
  if (n < N_SEQ - 1) ce = lse - gout[m * (K_TOP + 1) + K_TOP];

  const float g = gout[m * (K_TOP + 1) + lane];
  float gM = g;
  for (int s = 1; s < 64; s <<= 1) gM = fmaxf(gM, __shfl_xor(gM, s));
  float gE = __expf(g - gM);
  float gS = gE;
  for (int s = 1; s < 64; s <<= 1) gS += __shfl_xor(gS, s);
  const float lseK = gM + logf(gS);

  const float tl = t_lp[m * K_TOP + lane];
  const int mk = t_mask[m * K_TOP + lane];
  float kd = mk ? __expf(tl) * (tl - (g - lseK)) : 0.f;
  for (int s = 1; s < 64; s <<= 1) kd += __shfl_xor(kd, s);

  if (lane == 0) atomicAdd(out, 0.5f * kd + 0.5f * ce);
}

// ---------- launch ----------
extern "C" void kernel_launch(void* const* d_in, const int* in_sizes, int n_in,
                              void* d_out, int out_size, void* d_ws, size_t ws_size,
                              hipStream_t stream) {
  const float* x   = (const float*)d_in[0];   // [2,2048,2048]
  const float* Wm  = (const float*)d_in[1];   // [32768,2048]
  const int* tids  = (const int*)d_in[2];     // [2,2048,64]
  const float* tlp = (const float*)d_in[3];   // [2,2048,64]
  const int* tmask = (const int*)d_in[4];     // [2,2048,64]
  const int* tlab  = (const int*)d_in[5];     // [2,2048]
  float* out = (float*)d_out;

  char* ws = (char*)d_ws;
  unsigned char* w8 = (unsigned char*)ws;                                  // 64 MB
  unsigned char* x8 = (unsigned char*)(ws + (size_t)V_DIM * D_DIM);        // 8 MB
  char* p = ws + (size_t)V_DIM * D_DIM + (size_t)M_DIM * D_DIM;
  float* pMax = (float*)p;                       p += (size_t)M_DIM * NSLOT * 4;
  float* pSum = (float*)p;                       p += (size_t)M_DIM * NSLOT * 4;
  float* gout = (float*)p;                       p += (size_t)M_DIM * (K_TOP + 1) * 4;
  unsigned int* bcnt = (unsigned int*)p;         p += 2048 * 4;
  unsigned int* ebuf = (unsigned int*)p;         p += (size_t)2048 * EBCAP * 4;

  hipMemsetAsync(d_out, 0, sizeof(float), stream);
  hipMemsetAsync(bcnt, 0, 2048 * 4, stream);

  bin_kernel<<<(M_DIM * (K_TOP + 1) + 255) / 256, 256, 0, stream>>>(
      tids, tlab, bcnt, ebuf);

  cast_fp8_kernel<<<8192, 256, 0, stream>>>(
      (const float4*)Wm, (uint2*)w8, (V_DIM * D_DIM) / 8,
      (const float4*)x, (uint2*)x8, (M_DIM * D_DIM) / 8);

  gemm_lse_kernel<<<(M_DIM / 256) * (V_DIM / 256), 512, 0, stream>>>(
      x8, w8, pMax, pSum, bcnt, ebuf, gout);

  reduce_kernel<<<M_DIM / 4, 256, 0, stream>>>(pMax, pSum, gout, tlp, tmask, out);
}

// Round 13
// 503.201 us; speedup vs baseline: 1.2635x; 1.2635x over previous
//
#include <hip/hip_runtime.h>
#include <hip/hip_bf16.h>
#include <stdint.h>

typedef __attribute__((ext_vector_type(4))) float f32x4;
typedef __attribute__((ext_vector_type(2))) long l8x16;   // 16 fp8 bytes (2 MFMA ops)

#define D_DIM 2048
#define V_DIM 32768
#define M_DIM 4096
#define N_SEQ 2048
#define K_TOP 64
#define NSLOT 512   // 128 v-tiles * 4 w
#define EBCAP 256   // entries per 128x256 tile (avg ~65)
#define WSCALE 64.0f
#define IWSCALE 0.015625f

// ---------- helpers ----------
static __device__ __forceinline__ unsigned int f32_to_e4m3(float x) {
  float ax = fminf(fabsf(x), 448.0f);
  unsigned int s = (__float_as_uint(x) >> 31) << 7;
  if (ax >= 0.015625f) {
    unsigned int m = __float_as_uint(ax);
    unsigned int keep = m >> 20;
    unsigned int rb = (m >> 19) & 1u, st = (m & 0x7FFFFu) != 0u;
    keep += rb & (st | (keep & 1u));
    int v = (int)keep - (120 << 3);
    if (v > 0x7E) v = 0x7E;
    return s | (unsigned int)v;
  } else {
    int m = __float2int_rn(ax * 512.0f);
    return s | (unsigned int)m;
  }
}

typedef __attribute__((address_space(3))) unsigned int lds_u32_t;
typedef const __attribute__((address_space(1))) unsigned int glb_u32_t;
static __device__ __forceinline__ void gload16(const void* g, void* l) {
  __builtin_amdgcn_global_load_lds((glb_u32_t*)g, (lds_u32_t*)l, 16, 0, 0);
}

// ---------- cast f32 -> fp8 e4m3, PACKED layout (r11-verified) ----------
// Packed 64-B k-block: position q*16 holds [k 8q..8q+8) ++ [k 32+8q..+8).
__global__ void cast_fp8_kernel(const float4* __restrict__ inA, uint2* __restrict__ outA, int nA8,
                                const float4* __restrict__ inB, uint2* __restrict__ outB, int nB8) {
  int i = blockIdx.x * blockDim.x + threadIdx.x;
  int stride = gridDim.x * blockDim.x;
  int tot = nA8 + nB8;
  for (; i < tot; i += stride) {
    const float4* in = (i < nA8) ? inA : inB;
    uint2* out = (i < nA8) ? outA : outB;
    float sc = (i < nA8) ? WSCALE : 1.0f;
    int j = (i < nA8) ? i : i - nA8;
    float4 a = in[2 * j], b = in[2 * j + 1];
    uint2 r;
    r.x = f32_to_e4m3(a.x * sc) | (f32_to_e4m3(a.y * sc) << 8) |
          (f32_to_e4m3(a.z * sc) << 16) | (f32_to_e4m3(a.w * sc) << 24);
    r.y = f32_to_e4m3(b.x * sc) | (f32_to_e4m3(b.y * sc) << 8) |
          (f32_to_e4m3(b.z * sc) << 16) | (f32_to_e4m3(b.w * sc) << 24);
    int oj = ((j >> 3) << 3) + ((j & 3) << 1) + ((j >> 2) & 1);
    out[oj] = r;
  }
}

// ---------- binning: (m, id) -> per-(mt,vt)-tile entry lists ----------
// Tiles now 128x256: 32 mt x 128 vt = 4096 tiles.
__global__ __launch_bounds__(256) void bin_kernel(
    const int* __restrict__ tids, const int* __restrict__ tlab,
    unsigned int* __restrict__ cnt, unsigned int* __restrict__ ebuf) {
  int idx = blockIdx.x * 256 + threadIdx.x;
  if (idx >= M_DIM * (K_TOP + 1)) return;
  int m = idx / (K_TOP + 1), k = idx - m * (K_TOP + 1);
  int id;
  if (k < K_TOP) id = tids[m * K_TOP + k];
  else {
    int n = m & (N_SEQ - 1);
    if (n == N_SEQ - 1) return;   // no gold for last position
    id = tlab[m + 1];
  }
  int tile = ((m >> 7) << 7) + (id >> 8);   // mt*128 + vt
  unsigned int pos = atomicAdd(&cnt[tile], 1u);
  if (pos < EBCAP)
    ebuf[tile * EBCAP + pos] =
        ((unsigned int)k << 16) | ((unsigned int)(m & 127) << 8) | (unsigned int)(id & 255);
}

// ---------- 128x256 GEMM, fp8 16x16x32 MFMA, 4 waves, 2 blocks/CU ----------
// 4 waves (1M x 4N), per-wave 128x64 out (same as r11). BK=64 (64 B/row fp8
// packed). LDS 48KB: dbuf of 3 x 8KB halves {pos0=B[0:128), pos1=B[128:256),
// pos2=A}. r11 granule swizzle p = kqg ^ ((R>>1)&3), pre-applied on src.
// 4 segments/tile, 1 barrier each; stage tile T+2 (3 STAGEs x 2 loads);
// VMC(4) at s3 drains tile T+1 before s4's next-tile frag reads.

#define BAR do { __builtin_amdgcn_s_barrier(); asm volatile("" ::: "memory"); } while (0)
#define VMC(N) asm volatile("s_waitcnt vmcnt(" #N ")" ::: "memory")
#define PRIO1 __builtin_amdgcn_s_setprio(1)
#define PRIO0 __builtin_amdgcn_s_setprio(0)

#define LDF(BASE, R) \
  (*(const l8x16*)((BASE) + (R) * 64 + ((kqg ^ (((R) >> 1) & 3)) << 4)))
#define LDAF(BASE, MI) LDF(BASE, (MI) * 16 + fr)
#define LDBF(BASE, NI) LDF(BASE, brow + (NI) * 16 + fr)

#define STAGE(TT, POS) do { \
  char* dst_ = ldst + (((TT) & 1) ? 24576 : 0) + ((POS) << 13); \
  const unsigned char* src_ = (((POS) == 2) ? aptr : bptr) \
      + (((POS) == 1) ? (size_t)128 * D_DIM : (size_t)0) + (size_t)(TT) * 64; \
  gload16(src_, dst_); \
  gload16(src_ + (size_t)64 * D_DIM, dst_ + 4096); \
} while (0)

// dependent acc reuse distance = 8 MFMAs (ks0 sweep then ks1 sweep)
#define MFMA_Q(M0, U0, U1) do { \
  _Pragma("unroll") \
  for (int ni = 0; ni < 4; ++ni) \
    acc[M0][ni] = __builtin_amdgcn_mfma_f32_16x16x32_fp8_fp8((U0)[0], bF[ni][0], acc[M0][ni], 0, 0, 0); \
  _Pragma("unroll") \
  for (int ni = 0; ni < 4; ++ni) \
    acc[(M0) + 1][ni] = __builtin_amdgcn_mfma_f32_16x16x32_fp8_fp8((U1)[0], bF[ni][0], acc[(M0) + 1][ni], 0, 0, 0); \
  _Pragma("unroll") \
  for (int ni = 0; ni < 4; ++ni) \
    acc[M0][ni] = __builtin_amdgcn_mfma_f32_16x16x32_fp8_fp8((U0)[1], bF[ni][1], acc[M0][ni], 0, 0, 0); \
  _Pragma("unroll") \
  for (int ni = 0; ni < 4; ++ni) \
    acc[(M0) + 1][ni] = __builtin_amdgcn_mfma_f32_16x16x32_fp8_fp8((U1)[1], bF[ni][1], acc[(M0) + 1][ni], 0, 0, 0); \
} while (0)

// Entering invariant: bF = B(T), a01 = A mi0,1 of T (read in s4 of T-1 / prologue).
#define TILE1B(T, DOST, NVM, DONEXT) do { \
  char* base_ = lds + (((T) & 1) ? 24576 : 0); \
  char* nbase_ = lds + ((((T) + 1) & 1) ? 24576 : 0); \
  char* curA_ = base_ + 16384; \
  char* nxtA_ = nbase_ + 16384; \
  char* nxtB_ = nbase_ + bOff; \
  /* s1 */ \
  BAR; \
  if (DOST) STAGE((T) + 2, 0); \
  PRIO1; MFMA_Q(0, a01[0], a01[1]); PRIO0; \
  a23[0] = LDAF(curA_, 2); a23[1] = LDAF(curA_, 3); \
  /* s2 */ \
  BAR; \
  if (DOST) STAGE((T) + 2, 1); \
  PRIO1; MFMA_Q(2, a23[0], a23[1]); PRIO0; \
  a45[0] = LDAF(curA_, 4); a45[1] = LDAF(curA_, 5); \
  /* s3 */ \
  BAR; \
  PRIO1; MFMA_Q(4, a45[0], a45[1]); PRIO0; \
  a67[0] = LDAF(curA_, 6); a67[1] = LDAF(curA_, 7); \
  if ((NVM) == 4) { VMC(4); } else if ((NVM) == 0) { VMC(0); } \
  /* s4 */ \
  BAR; \
  if (DOST) STAGE((T) + 2, 2); \
  PRIO1; MFMA_Q(6, a67[0], a67[1]); PRIO0; \
  if (DONEXT) { \
    bF[0] = LDBF(nxtB_, 0); bF[1] = LDBF(nxtB_, 1); \
    bF[2] = LDBF(nxtB_, 2); bF[3] = LDBF(nxtB_, 3); \
    a01[0] = LDAF(nxtA_, 0); a01[1] = LDAF(nxtA_, 1); \
  } \
} while (0)

__global__ __launch_bounds__(256, 2) void gemm_lse_kernel(
    const unsigned char* __restrict__ x8,     // [M_DIM][D_DIM] fp8 packed
    const unsigned char* __restrict__ w8,     // [V_DIM][D_DIM] fp8 packed (x64)
    float* __restrict__ pMax,                 // [M_DIM][NSLOT]
    float* __restrict__ pSum,
    const unsigned int* __restrict__ bcnt,    // [4096]
    const unsigned int* __restrict__ ebuf,    // [4096][EBCAP]
    float* __restrict__ gout) {               // [M_DIM][K_TOP+1]
  __shared__ __align__(16) char lds[49152];   // 2 x 24KB (3 x 8KB halves)

  // Locality mapping: 512 resident blocks = 32mt x 16vt; XCD pinned to
  // 2 vt columns (1MB W slice -> L2-resident).
  const int bid0 = blockIdx.x;
  const int mt = (bid0 >> 4) & 31;
  const int vt = ((bid0 >> 9) << 4) | (bid0 & 15);
  const int tid = threadIdx.x, lane = tid & 63, w = tid >> 6;   // 4 waves
  const int fr = lane & 15, kqg = lane >> 4;
  const int brow = (w & 1) * 64;
  const int bOff = (w >> 1) << 13;   // B half: pos0 (w=0,1) / pos1 (w=2,3)

  // staging: thread t -> row t>>2 (+64 second load), granule pos t&3;
  // src pos pre-swizzled (p ^ (row>>1)&3)
  const int gcol = (((tid & 3) ^ ((tid >> 3) & 3)) << 4);
  const unsigned char* aptr = x8 + (size_t)(mt * 128 + (tid >> 2)) * D_DIM + gcol;
  const unsigned char* bptr = w8 + (size_t)(vt * 256 + (tid >> 2)) * D_DIM + gcol;
  char* ldst = lds + tid * 16;

  f32x4 acc[8][4];
#pragma unroll
  for (int i = 0; i < 8; i++)
#pragma unroll
    for (int j = 0; j < 4; j++) acc[i][j] = (f32x4){0.f, 0.f, 0.f, 0.f};

  l8x16 bF[4], a01[2], a23[2], a45[2], a67[2];

  // prologue: stage tiles 0 and 1 fully, drain, pre-read tile0 frags
  STAGE(0, 0); STAGE(0, 1); STAGE(0, 2);
  STAGE(1, 0); STAGE(1, 1); STAGE(1, 2);
  VMC(0);
  BAR;
  {
    char* b0_ = lds + bOff;
    char* a0_ = lds + 16384;
    bF[0] = LDBF(b0_, 0); bF[1] = LDBF(b0_, 1);
    bF[2] = LDBF(b0_, 2); bF[3] = LDBF(b0_, 3);
    a01[0] = LDAF(a0_, 0); a01[1] = LDAF(a0_, 1);
  }

  // main loop: tiles 0..29 stage tile T+2; tail tiles 30, 31
  for (int it = 0; it < 15; ++it) {
    TILE1B(2 * it, 1, 4, 1);
    TILE1B(2 * it + 1, 1, 4, 1);
  }
  TILE1B(30, 0, 0, 1);
  TILE1B(31, 0, 99, 0);

  // ---- epilogue A: per-row (max, sumexp); descale acc by 1/64 ----
  const int slot = vt * 4 + w;
#pragma unroll
  for (int mi = 0; mi < 8; mi++) {
#pragma unroll
    for (int j = 0; j < 4; j++) {
      const int row = mt * 128 + mi * 16 + kqg * 4 + j;
      float v0 = acc[mi][0][j] * IWSCALE, v1 = acc[mi][1][j] * IWSCALE;
      float v2 = acc[mi][2][j] * IWSCALE, v3 = acc[mi][3][j] * IWSCALE;
      float mx = fmaxf(fmaxf(v0, v1), fmaxf(v2, v3));
      for (int s = 1; s < 16; s <<= 1) mx = fmaxf(mx, __shfl_xor(mx, s));
      float sm = __expf(v0 - mx) + __expf(v1 - mx) +
                 __expf(v2 - mx) + __expf(v3 - mx);
      for (int s = 1; s < 16; s <<= 1) sm += __shfl_xor(sm, s);
      if (fr == 0) {
        pMax[row * NSLOT + slot] = mx;
        pSum[row * NSLOT + slot] = sm;
      }
    }
  }

  // ---- epilogue B: fused gather via LDS round-trip, 4 passes of 32 rows ----
  const int tile = (mt << 7) + vt;
  unsigned int cn = bcnt[tile];
  if (cn > EBCAP) cn = EBCAP;
  const unsigned int* elist = ebuf + tile * EBCAP;
  float* ldsf = (float*)lds;

  __syncthreads();
#pragma unroll
  for (int pass = 0; pass < 4; ++pass) {
#pragma unroll
    for (int mm = 0; mm < 2; ++mm) {
      const int mi = 2 * pass + mm;
      const int r0 = mm * 16 + kqg * 4;
      const int cs = (kqg & 1) << 4;
#pragma unroll
      for (int ni = 0; ni < 4; ni++) {
        const int c0 = (w * 64 + ni * 16 + fr) ^ cs;
#pragma unroll
        for (int j = 0; j < 4; j++)
          ldsf[(r0 + j) * 256 + c0] = acc[mi][ni][j] * IWSCALE;
      }
    }
    __syncthreads();
    for (unsigned int e = tid; e < cn; e += 256) {
      unsigned int u = elist[e];
      int r = (u >> 8) & 255;
      if ((r >> 5) == pass) {
        int c = u & 255, k = u >> 16;
        int rl = r & 31;
        gout[(mt * 128 + r) * (K_TOP + 1) + k] = ldsf[rl * 256 + (c ^ (((rl >> 2) & 1) << 4))];
      }
    }
    __syncthreads();
  }
}

// ---------- final: lse merge + CE + KD, atomic into scalar ----------
__global__ __launch_bounds__(256) void reduce_kernel(
    const float* __restrict__ pMax, const float* __restrict__ pSum,
    const float* __restrict__ gout, const float* __restrict__ t_lp,
    const int* __restrict__ t_mask, float* __restrict__ out) {
  const int tid = threadIdx.x, lane = tid & 63, w = tid >> 6;
  const int m = blockIdx.x * 4 + w;

  float msl[8], ssl[8];
  float M = -1e30f;
#pragma unroll
  for (int j = 0; j < 8; j++) {
    msl[j] = pMax[m * NSLOT + lane + j * 64];
    ssl[j] = pSum[m * NSLOT + lane + j * 64];
    M = fmaxf(M, msl[j]);
  }
  for (int s = 1; s < 64; s <<= 1) M = fmaxf(M, __shfl_xor(M, s));
  float S = 0.f;
#pragma unroll
  for (int j = 0; j < 8; j++) S += ssl[j] * __expf(msl[j] - M);
  for (int s = 1; s < 64; s <<= 1) S += __shfl_xor(S, s);
  const float lse = M + logf(S);

  const int n = m & (N_SEQ - 1);
  float ce = 0.f;
  if (n < N_SEQ - 1) ce = lse - gout[m * (K_TOP + 1) + K_TOP];

  const float g = gout[m * (K_TOP + 1) + lane];
  float gM = g;
  for (int s = 1; s < 64; s <<= 1) gM = fmaxf(gM, __shfl_xor(gM, s));
  float gE = __expf(g - gM);
  float gS = gE;
  for (int s = 1; s < 64; s <<= 1) gS += __shfl_xor(gS, s);
  const float lseK = gM + logf(gS);

  const float tl = t_lp[m * K_TOP + lane];
  const int mk = t_mask[m * K_TOP + lane];
  float kd = mk ? __expf(tl) * (tl - (g - lseK)) : 0.f;
  for (int s = 1; s < 64; s <<= 1) kd += __shfl_xor(kd, s);

  if (lane == 0) atomicAdd(out, 0.5f * kd + 0.5f * ce);
}

// ---------- launch ----------
extern "C" void kernel_launch(void* const* d_in, const int* in_sizes, int n_in,
                              void* d_out, int out_size, void* d_ws, size_t ws_size,
                              hipStream_t stream) {
  const float* x   = (const float*)d_in[0];   // [2,2048,2048]
  const float* Wm  = (const float*)d_in[1];   // [32768,2048]
  const int* tids  = (const int*)d_in[2];     // [2,2048,64]
  const float* tlp = (const float*)d_in[3];   // [2,2048,64]
  const int* tmask = (const int*)d_in[4];     // [2,2048,64]
  const int* tlab  = (const int*)d_in[5];     // [2,2048]
  float* out = (float*)d_out;

  char* ws = (char*)d_ws;
  unsigned char* w8 = (unsigned char*)ws;                                  // 64 MB
  unsigned char* x8 = (unsigned char*)(ws + (size_t)V_DIM * D_DIM);        // 8 MB
  char* p = ws + (size_t)V_DIM * D_DIM + (size_t)M_DIM * D_DIM;
  float* pMax = (float*)p;                       p += (size_t)M_DIM * NSLOT * 4;
  float* pSum = (float*)p;                       p += (size_t)M_DIM * NSLOT * 4;
  float* gout = (float*)p;                       p += (size_t)M_DIM * (K_TOP + 1) * 4;
  unsigned int* bcnt = (unsigned int*)p;         p += 4096 * 4;
  unsigned int* ebuf = (unsigned int*)p;         p += (size_t)4096 * EBCAP * 4;

  hipMemsetAsync(d_out, 0, sizeof(float), stream);
  hipMemsetAsync(bcnt, 0, 4096 * 4, stream);

  bin_kernel<<<(M_DIM * (K_TOP + 1) + 255) / 256, 256, 0, stream>>>(
      tids, tlab, bcnt, ebuf);

  cast_fp8_kernel<<<8192, 256, 0, stream>>>(
      (const float4*)Wm, (uint2*)w8, (V_DIM * D_DIM) / 8,
      (const float4*)x, (uint2*)x8, (M_DIM * D_DIM) / 8);

  gemm_lse_kernel<<<(M_DIM / 128) * (V_DIM / 256), 256, 0, stream>>>(
      x8, w8, pMax, pSum, bcnt, ebuf, gout);

  reduce_kernel<<<M_DIM / 4, 256, 0, stream>>>(pMax, pSum, gout, tlp, tmask, out);
}

// Round 14
// 498.400 us; speedup vs baseline: 1.2757x; 1.0096x over previous
//
#include <hip/hip_runtime.h>
#include <hip/hip_bf16.h>
#include <stdint.h>

typedef __attribute__((ext_vector_type(4))) float f32x4;
typedef __attribute__((ext_vector_type(2))) long l8x16;   // 16 fp8 bytes (2 MFMA ops)

#define D_DIM 2048
#define V_DIM 32768
#define M_DIM 4096
#define N_SEQ 2048
#define K_TOP 64
#define NSLOT 512   // 128 v-tiles * 4 w
#define EBCAP 256   // entries per 128x256 tile (avg ~65)
#define WSCALE 64.0f
#define IWSCALE 0.015625f

// ---------- helpers ----------
static __device__ __forceinline__ unsigned int f32_to_e4m3(float x) {
  float ax = fminf(fabsf(x), 448.0f);
  unsigned int s = (__float_as_uint(x) >> 31) << 7;
  if (ax >= 0.015625f) {
    unsigned int m = __float_as_uint(ax);
    unsigned int keep = m >> 20;
    unsigned int rb = (m >> 19) & 1u, st = (m & 0x7FFFFu) != 0u;
    keep += rb & (st | (keep & 1u));
    int v = (int)keep - (120 << 3);
    if (v > 0x7E) v = 0x7E;
    return s | (unsigned int)v;
  } else {
    int m = __float2int_rn(ax * 512.0f);
    return s | (unsigned int)m;
  }
}

typedef __attribute__((address_space(3))) unsigned int lds_u32_t;
typedef const __attribute__((address_space(1))) unsigned int glb_u32_t;
static __device__ __forceinline__ void gload16(const void* g, void* l) {
  __builtin_amdgcn_global_load_lds((glb_u32_t*)g, (lds_u32_t*)l, 16, 0, 0);
}

// ---------- cast f32 -> fp8 e4m3, PACKED layout (r11-verified) ----------
// Packed 64-B k-block: position q*16 holds [k 8q..8q+8) ++ [k 32+8q..+8).
__global__ void cast_fp8_kernel(const float4* __restrict__ inA, uint2* __restrict__ outA, int nA8,
                                const float4* __restrict__ inB, uint2* __restrict__ outB, int nB8) {
  int i = blockIdx.x * blockDim.x + threadIdx.x;
  int stride = gridDim.x * blockDim.x;
  int tot = nA8 + nB8;
  for (; i < tot; i += stride) {
    const float4* in = (i < nA8) ? inA : inB;
    uint2* out = (i < nA8) ? outA : outB;
    float sc = (i < nA8) ? WSCALE : 1.0f;
    int j = (i < nA8) ? i : i - nA8;
    float4 a = in[2 * j], b = in[2 * j + 1];
    uint2 r;
    r.x = f32_to_e4m3(a.x * sc) | (f32_to_e4m3(a.y * sc) << 8) |
          (f32_to_e4m3(a.z * sc) << 16) | (f32_to_e4m3(a.w * sc) << 24);
    r.y = f32_to_e4m3(b.x * sc) | (f32_to_e4m3(b.y * sc) << 8) |
          (f32_to_e4m3(b.z * sc) << 16) | (f32_to_e4m3(b.w * sc) << 24);
    int oj = ((j >> 3) << 3) + ((j & 3) << 1) + ((j >> 2) & 1);
    out[oj] = r;
  }
}

// ---------- binning: (m, id) -> per-(mt,vt)-tile entry lists ----------
// Tiles 128x256: 32 mt x 128 vt = 4096 tiles.
__global__ __launch_bounds__(256) void bin_kernel(
    const int* __restrict__ tids, const int* __restrict__ tlab,
    unsigned int* __restrict__ cnt, unsigned int* __restrict__ ebuf) {
  int idx = blockIdx.x * 256 + threadIdx.x;
  if (idx >= M_DIM * (K_TOP + 1)) return;
  int m = idx / (K_TOP + 1), k = idx - m * (K_TOP + 1);
  int id;
  if (k < K_TOP) id = tids[m * K_TOP + k];
  else {
    int n = m & (N_SEQ - 1);
    if (n == N_SEQ - 1) return;   // no gold for last position
    id = tlab[m + 1];
  }
  int tile = ((m >> 7) << 7) + (id >> 8);   // mt*128 + vt
  unsigned int pos = atomicAdd(&cnt[tile], 1u);
  if (pos < EBCAP)
    ebuf[tile * EBCAP + pos] =
        ((unsigned int)k << 16) | ((unsigned int)(m & 127) << 8) | (unsigned int)(id & 255);
}

// ---------- 128x256 GEMM, fp8 16x16x32 MFMA, 4 waves, 2 blocks/CU ----------
// 2 barriers/tile. segA = {BAR; stage (T+2)h0,h1; MFMA mi0-3; read a45,a67;
// VMC(4)}; segB = {BAR; stage (T+2)h2; MFMA mi4-7; read bF,a01,a23 of T+1}.
// VMC(4) at segA end leaves only (T+2)h0,h1 outstanding -> T+1 landed before
// segB's barrier, so T+1 reads after it are safe. Buffer overwrites all have
// last-read >= 1 barrier earlier (audit in round notes).
// LDS 48KB/block: dbuf of 3 x 8KB halves {pos0=B[0:128), pos1=B[128:256),
// pos2=A}. r11 granule swizzle p = kqg ^ ((R>>1)&3), pre-applied on src.

#define BAR do { __builtin_amdgcn_s_barrier(); asm volatile("" ::: "memory"); } while (0)
#define VMC(N) asm volatile("s_waitcnt vmcnt(" #N ")" ::: "memory")
#define PRIO1 __builtin_amdgcn_s_setprio(1)
#define PRIO0 __builtin_amdgcn_s_setprio(0)

#define LDF(BASE, R) \
  (*(const l8x16*)((BASE) + (R) * 64 + ((kqg ^ (((R) >> 1) & 3)) << 4)))
#define LDAF(BASE, MI) LDF(BASE, (MI) * 16 + fr)
#define LDBF(BASE, NI) LDF(BASE, brow + (NI) * 16 + fr)

#define STAGE(TT, POS) do { \
  char* dst_ = ldst + (((TT) & 1) ? 24576 : 0) + ((POS) << 13); \
  const unsigned char* src_ = (((POS) == 2) ? aptr : bptr) \
      + (((POS) == 1) ? (size_t)128 * D_DIM : (size_t)0) + (size_t)(TT) * 64; \
  gload16(src_, dst_); \
  gload16(src_ + (size_t)64 * D_DIM, dst_ + 4096); \
} while (0)

// dependent acc reuse distance = 8 MFMAs (ks0 sweep then ks1 sweep)
#define MFMA_Q(M0, U0, U1) do { \
  _Pragma("unroll") \
  for (int ni = 0; ni < 4; ++ni) \
    acc[M0][ni] = __builtin_amdgcn_mfma_f32_16x16x32_fp8_fp8((U0)[0], bF[ni][0], acc[M0][ni], 0, 0, 0); \
  _Pragma("unroll") \
  for (int ni = 0; ni < 4; ++ni) \
    acc[(M0) + 1][ni] = __builtin_amdgcn_mfma_f32_16x16x32_fp8_fp8((U1)[0], bF[ni][0], acc[(M0) + 1][ni], 0, 0, 0); \
  _Pragma("unroll") \
  for (int ni = 0; ni < 4; ++ni) \
    acc[M0][ni] = __builtin_amdgcn_mfma_f32_16x16x32_fp8_fp8((U0)[1], bF[ni][1], acc[M0][ni], 0, 0, 0); \
  _Pragma("unroll") \
  for (int ni = 0; ni < 4; ++ni) \
    acc[(M0) + 1][ni] = __builtin_amdgcn_mfma_f32_16x16x32_fp8_fp8((U1)[1], bF[ni][1], acc[(M0) + 1][ni], 0, 0, 0); \
} while (0)

// Entering invariant: bF = B(T), a01/a23 = A mi0..3 of T (read in segB of T-1 / prologue).
#define TILE2SEG(T, DOST, NVM, DONEXT) do { \
  char* base_ = lds + (((T) & 1) ? 24576 : 0); \
  char* nbase_ = lds + ((((T) + 1) & 1) ? 24576 : 0); \
  char* curA_ = base_ + 16384; \
  char* nxtA_ = nbase_ + 16384; \
  char* nxtB_ = nbase_ + bOff; \
  /* segA */ \
  BAR; \
  if (DOST) { STAGE((T) + 2, 0); STAGE((T) + 2, 1); } \
  PRIO1; MFMA_Q(0, a01[0], a01[1]); MFMA_Q(2, a23[0], a23[1]); PRIO0; \
  a45[0] = LDAF(curA_, 4); a45[1] = LDAF(curA_, 5); \
  a67[0] = LDAF(curA_, 6); a67[1] = LDAF(curA_, 7); \
  if ((NVM) == 4) { VMC(4); } else if ((NVM) == 0) { VMC(0); } \
  /* segB */ \
  BAR; \
  if (DOST) STAGE((T) + 2, 2); \
  PRIO1; MFMA_Q(4, a45[0], a45[1]); MFMA_Q(6, a67[0], a67[1]); PRIO0; \
  if (DONEXT) { \
    bF[0] = LDBF(nxtB_, 0); bF[1] = LDBF(nxtB_, 1); \
    bF[2] = LDBF(nxtB_, 2); bF[3] = LDBF(nxtB_, 3); \
    a01[0] = LDAF(nxtA_, 0); a01[1] = LDAF(nxtA_, 1); \
    a23[0] = LDAF(nxtA_, 2); a23[1] = LDAF(nxtA_, 3); \
  } \
} while (0)

__global__ __launch_bounds__(256, 2) void gemm_lse_kernel(
    const unsigned char* __restrict__ x8,     // [M_DIM][D_DIM] fp8 packed
    const unsigned char* __restrict__ w8,     // [V_DIM][D_DIM] fp8 packed (x64)
    float* __restrict__ pMax,                 // [M_DIM][NSLOT]
    float* __restrict__ pSum,
    const unsigned int* __restrict__ bcnt,    // [4096]
    const unsigned int* __restrict__ ebuf,    // [4096][EBCAP]
    float* __restrict__ gout) {               // [M_DIM][K_TOP+1]
  __shared__ __align__(16) char lds[49152];   // 2 x 24KB (3 x 8KB halves)

  // Locality mapping: 512 resident blocks = 32mt x 16vt; XCD pinned to
  // 2 vt columns (1MB W slice -> L2-resident).
  const int bid0 = blockIdx.x;
  const int mt = (bid0 >> 4) & 31;
  const int vt = ((bid0 >> 9) << 4) | (bid0 & 15);
  const int tid = threadIdx.x, lane = tid & 63, w = tid >> 6;   // 4 waves
  const int fr = lane & 15, kqg = lane >> 4;
  const int brow = (w & 1) * 64;
  const int bOff = (w >> 1) << 13;   // B half: pos0 (w=0,1) / pos1 (w=2,3)

  // staging: thread t -> row t>>2 (+64 second load), granule pos t&3;
  // src pos pre-swizzled (p ^ (row>>1)&3)
  const int gcol = (((tid & 3) ^ ((tid >> 3) & 3)) << 4);
  const unsigned char* aptr = x8 + (size_t)(mt * 128 + (tid >> 2)) * D_DIM + gcol;
  const unsigned char* bptr = w8 + (size_t)(vt * 256 + (tid >> 2)) * D_DIM + gcol;
  char* ldst = lds + tid * 16;

  f32x4 acc[8][4];
#pragma unroll
  for (int i = 0; i < 8; i++)
#pragma unroll
    for (int j = 0; j < 4; j++) acc[i][j] = (f32x4){0.f, 0.f, 0.f, 0.f};

  l8x16 bF[4], a01[2], a23[2], a45[2], a67[2];

  // prologue: stage tiles 0 and 1 fully, drain, pre-read tile0 frags
  STAGE(0, 0); STAGE(0, 1); STAGE(0, 2);
  STAGE(1, 0); STAGE(1, 1); STAGE(1, 2);
  VMC(0);
  BAR;
  {
    char* b0_ = lds + bOff;
    char* a0_ = lds + 16384;
    bF[0] = LDBF(b0_, 0); bF[1] = LDBF(b0_, 1);
    bF[2] = LDBF(b0_, 2); bF[3] = LDBF(b0_, 3);
    a01[0] = LDAF(a0_, 0); a01[1] = LDAF(a0_, 1);
    a23[0] = LDAF(a0_, 2); a23[1] = LDAF(a0_, 3);
  }

  // main loop: tiles 0..29 stage tile T+2; tail tiles 30, 31
  for (int it = 0; it < 15; ++it) {
    TILE2SEG(2 * it, 1, 4, 1);
    TILE2SEG(2 * it + 1, 1, 4, 1);
  }
  TILE2SEG(30, 0, 0, 1);
  TILE2SEG(31, 0, 99, 0);

  // ---- epilogue A: per-row (max, sumexp); descale acc by 1/64 ----
  const int slot = vt * 4 + w;
#pragma unroll
  for (int mi = 0; mi < 8; mi++) {
#pragma unroll
    for (int j = 0; j < 4; j++) {
      const int row = mt * 128 + mi * 16 + kqg * 4 + j;
      float v0 = acc[mi][0][j] * IWSCALE, v1 = acc[mi][1][j] * IWSCALE;
      float v2 = acc[mi][2][j] * IWSCALE, v3 = acc[mi][3][j] * IWSCALE;
      float mx = fmaxf(fmaxf(v0, v1), fmaxf(v2, v3));
      for (int s = 1; s < 16; s <<= 1) mx = fmaxf(mx, __shfl_xor(mx, s));
      float sm = __expf(v0 - mx) + __expf(v1 - mx) +
                 __expf(v2 - mx) + __expf(v3 - mx);
      for (int s = 1; s < 16; s <<= 1) sm += __shfl_xor(sm, s);
      if (fr == 0) {
        pMax[row * NSLOT + slot] = mx;
        pSum[row * NSLOT + slot] = sm;
      }
    }
  }

  // ---- epilogue B: fused gather via LDS round-trip, 4 passes of 32 rows ----
  const int tile = (mt << 7) + vt;
  unsigned int cn = bcnt[tile];
  if (cn > EBCAP) cn = EBCAP;
  const unsigned int* elist = ebuf + tile * EBCAP;
  float* ldsf = (float*)lds;

  __syncthreads();
#pragma unroll
  for (int pass = 0; pass < 4; ++pass) {
#pragma unroll
    for (int mm = 0; mm < 2; ++mm) {
      const int mi = 2 * pass + mm;
      const int r0 = mm * 16 + kqg * 4;
      const int cs = (kqg & 1) << 4;
#pragma unroll
      for (int ni = 0; ni < 4; ni++) {
        const int c0 = (w * 64 + ni * 16 + fr) ^ cs;
#pragma unroll
        for (int j = 0; j < 4; j++)
          ldsf[(r0 + j) * 256 + c0] = acc[mi][ni][j] * IWSCALE;
      }
    }
    __syncthreads();
    for (unsigned int e = tid; e < cn; e += 256) {
      unsigned int u = elist[e];
      int r = (u >> 8) & 255;
      if ((r >> 5) == pass) {
        int c = u & 255, k = u >> 16;
        int rl = r & 31;
        gout[(mt * 128 + r) * (K_TOP + 1) + k] = ldsf[rl * 256 + (c ^ (((rl >> 2) & 1) << 4))];
      }
    }
    __syncthreads();
  }
}

// ---------- final: lse merge + CE + KD, atomic into scalar ----------
__global__ __launch_bounds__(256) void reduce_kernel(
    const float* __restrict__ pMax, const float* __restrict__ pSum,
    const float* __restrict__ gout, const float* __restrict__ t_lp,
    const int* __restrict__ t_mask, float* __restrict__ out) {
  const int tid = threadIdx.x, lane = tid & 63, w = tid >> 6;
  const int m = blockIdx.x * 4 + w;

  float msl[8], ssl[8];
  float M = -1e30f;
#pragma unroll
  for (int j = 0; j < 8; j++) {
    msl[j] = pMax[m * NSLOT + lane + j * 64];
    ssl[j] = pSum[m * NSLOT + lane + j * 64];
    M = fmaxf(M, msl[j]);
  }
  for (int s = 1; s < 64; s <<= 1) M = fmaxf(M, __shfl_xor(M, s));
  float S = 0.f;
#pragma unroll
  for (int j = 0; j < 8; j++) S += ssl[j] * __expf(msl[j] - M);
  for (int s = 1; s < 64; s <<= 1) S += __shfl_xor(S, s);
  const float lse = M + logf(S);

  const int n = m & (N_SEQ - 1);
  float ce = 0.f;
  if (n < N_SEQ - 1) ce = lse - gout[m * (K_TOP + 1) + K_TOP];

  const float g = gout[m * (K_TOP + 1) + lane];
  float gM = g;
  for (int s = 1; s < 64; s <<= 1) gM = fmaxf(gM, __shfl_xor(gM, s));
  float gE = __expf(g - gM);
  float gS = gE;
  for (int s = 1; s < 64; s <<= 1) gS += __shfl_xor(gS, s);
  const float lseK = gM + logf(gS);

  const float tl = t_lp[m * K_TOP + lane];
  const int mk = t_mask[m * K_TOP + lane];
  float kd = mk ? __expf(tl) * (tl - (g - lseK)) : 0.f;
  for (int s = 1; s < 64; s <<= 1) kd += __shfl_xor(kd, s);

  if (lane == 0) atomicAdd(out, 0.5f * kd + 0.5f * ce);
}

// ---------- launch ----------
extern "C" void kernel_launch(void* const* d_in, const int* in_sizes, int n_in,
                              void* d_out, int out_size, void* d_ws, size_t ws_size,
                              hipStream_t stream) {
  const float* x   = (const float*)d_in[0];   // [2,2048,2048]
  const float* Wm  = (const float*)d_in[1];   // [32768,2048]
  const int* tids  = (const int*)d_in[2];     // [2,2048,64]
  const float* tlp = (const float*)d_in[3];   // [2,2048,64]
  const int* tmask = (const int*)d_in[4];     // [2,2048,64]
  const int* tlab  = (const int*)d_in[5];     // [2,2048]
  float* out = (float*)d_out;

  char* ws = (char*)d_ws;
  unsigned char* w8 = (unsigned char*)ws;                                  // 64 MB
  unsigned char* x8 = (unsigned char*)(ws + (size_t)V_DIM * D_DIM);        // 8 MB
  char* p = ws + (size_t)V_DIM * D_DIM + (size_t)M_DIM * D_DIM;
  float* pMax = (float*)p;                       p += (size_t)M_DIM * NSLOT * 4;
  float* pSum = (float*)p;                       p += (size_t)M_DIM * NSLOT * 4;
  float* gout = (float*)p;                       p += (size_t)M_DIM * (K_TOP + 1) * 4;
  unsigned int* bcnt = (unsigned int*)p;         p += 4096 * 4;
  unsigned int* ebuf = (unsigned int*)p;         p += (size_t)4096 * EBCAP * 4;

  hipMemsetAsync(d_out, 0, sizeof(float), stream);
  hipMemsetAsync(bcnt, 0, 4096 * 4, stream);

  bin_kernel<<<(M_DIM * (K_TOP + 1) + 255) / 256, 256, 0, stream>>>(
      tids, tlab, bcnt, ebuf);

  cast_fp8_kernel<<<8192, 256, 0, stream>>>(
      (const float4*)Wm, (uint2*)w8, (V_DIM * D_DIM) / 8,
      (const float4*)x, (uint2*)x8, (M_DIM * D_DIM) / 8);

  gemm_lse_kernel<<<(M_DIM / 128) * (V_DIM / 256), 256, 0, stream>>>(
      x8, w8, pMax, pSum, bcnt, ebuf, gout);

  reduce_kernel<<<M_DIM / 4, 256, 0, stream>>>(pMax, pSum, gout, tlp, tmask, out);
}